// Round 6
// baseline (233.308 us; speedup 1.0000x reference)
//
#include <hip/hip_runtime.h>
#include <hip/hip_bf16.h>
#include <stdint.h>

#define S_LEN 2048
#define D_MODEL 768
#define NH 12
#define DK 64
#define BATCH 2
#define M_TOT (BATCH * S_LEN) /* 4096 */

typedef __attribute__((ext_vector_type(8))) short short8;
typedef __attribute__((ext_vector_type(4))) float f32x4;
typedef __attribute__((ext_vector_type(16))) float f32x16;

__device__ inline short f2bf(float f) {
  union { float f; uint32_t u; } v; v.f = f;
  uint32_t r = v.u + 0x7fffu + ((v.u >> 16) & 1u);
  return (short)(r >> 16);
}

__device__ inline f32x4 mfma16(short8 a, short8 b, f32x4 c) {
  return __builtin_amdgcn_mfma_f32_16x16x32_bf16(a, b, c, 0, 0, 0);
}
__device__ inline f32x16 mfma32(short8 a, short8 b, f32x16 c) {
  return __builtin_amdgcn_mfma_f32_32x32x16_bf16(a, b, c, 0, 0, 0);
}

__device__ inline void gl16(const void* g, void* l) {
  __builtin_amdgcn_global_load_lds(
      (const __attribute__((address_space(1))) unsigned*)g,
      (__attribute__((address_space(3))) unsigned*)l, 16, 0, 0);
}

__device__ inline unsigned cvtpk(float lo, float hi) {
  unsigned r;
  asm("v_cvt_pk_bf16_f32 %0, %1, %2" : "=v"(r) : "v"(lo), "v"(hi));
  return r;
}
__device__ inline void plswap(unsigned& a, unsigned& b) {
  asm("v_permlane32_swap_b32 %0, %1" : "+v"(a), "+v"(b));
}
__device__ inline float lo16(uint32_t u) {
  union { uint32_t u; float f; } x; x.u = u << 16; return x.f;
}
__device__ inline float hi16(uint32_t u) {
  union { uint32_t u; float f; } x; x.u = u & 0xffff0000u; return x.f;
}

// ---------------------------------------------------------------------------
// 1a) Weight transpose + bf16 cast (all 4 weights in one launch, z selects)
// ---------------------------------------------------------------------------
__global__ __launch_bounds__(256) void transpose_w_kernel(
    const float* __restrict__ Wq, const float* __restrict__ Wk,
    const float* __restrict__ Wv, const float* __restrict__ Wo,
    short* __restrict__ WT) {
  int z = blockIdx.z;
  const float* W = z == 0 ? Wq : (z == 1 ? Wk : (z == 2 ? Wv : Wo));
  short* O = WT + (size_t)z * D_MODEL * D_MODEL;
  __shared__ float t[32][33];
  int x = threadIdx.x, y = threadIdx.y;
  int nb = blockIdx.x * 32, kb = blockIdx.y * 32;
#pragma unroll
  for (int j = 0; j < 4; ++j)
    t[y + 8 * j][x] = W[(kb + y + 8 * j) * D_MODEL + nb + x];
  __syncthreads();
#pragma unroll
  for (int j = 0; j < 4; ++j)
    O[(nb + y + 8 * j) * D_MODEL + kb + x] = f2bf(t[x][y + 8 * j]);
}

// ---------------------------------------------------------------------------
// 1b) Activation cast fp32 -> bf16
// ---------------------------------------------------------------------------
__global__ __launch_bounds__(256) void cast_x_kernel(
    const float* __restrict__ Xq, const float* __restrict__ Xk,
    const float* __restrict__ Xv, short* __restrict__ Xb) {
  int z = blockIdx.y;
  const float* X = z == 0 ? Xq : (z == 1 ? Xk : Xv);
  short* O = Xb + (size_t)z * M_TOT * D_MODEL;
  size_t i = ((size_t)blockIdx.x * 256 + threadIdx.x) * 8;
  float4 f0 = *(const float4*)(X + i);
  float4 f1 = *(const float4*)(X + i + 4);
  short8 v;
  v[0] = f2bf(f0.x); v[1] = f2bf(f0.y); v[2] = f2bf(f0.z); v[3] = f2bf(f0.w);
  v[4] = f2bf(f1.x); v[5] = f2bf(f1.y); v[6] = f2bf(f1.z); v[7] = f2bf(f1.w);
  *(short8*)(O + i) = v;
}

// ---------------------------------------------------------------------------
// 2) Projections, m97-style 128x128 tile, BK=32, global_load_lds staging.
// ---------------------------------------------------------------------------
__global__ __launch_bounds__(256) void proj_kernel(
    const short* __restrict__ Xb, const short* __restrict__ WTall,
    short* __restrict__ Qo, short* __restrict__ Ko, short* __restrict__ Vo) {
  int bid = blockIdx.x;
  int wk = (bid & 7) * 72 + (bid >> 3);   // 576 % 8 == 0 -> bijective
  int which = wk / 192;
  int rem = wk % 192;
  int mt = rem / 6, nt = rem % 6;
  int mbase = mt * 128, nbase = nt * 128;
  const short* X = Xb + (size_t)which * M_TOT * D_MODEL;
  const short* WT = WTall + (size_t)which * D_MODEL * D_MODEL;

  __shared__ short As[128][32];
  __shared__ short Bs[128][32];
  int tid = threadIdx.x;
  int wv = tid >> 6, lane = tid & 63, r = lane & 15, g = lane >> 4;
  int wm = (wv & 1) * 64, wn = (wv >> 1) * 64;
  int srow = (lane >> 2), scol = (lane & 3) * 8;

  f32x4 acc[4][4] = {};
  for (int kk = 0; kk < D_MODEL; kk += 32) {
#pragma unroll
    for (int j = 0; j < 2; ++j) {
      int row = wv * 32 + j * 16;
      gl16(X + (size_t)(mbase + row + srow) * D_MODEL + kk + scol, &As[row][0]);
      gl16(WT + (size_t)(nbase + row + srow) * D_MODEL + kk + scol, &Bs[row][0]);
    }
    __syncthreads();
    short8 a[4], b[4];
#pragma unroll
    for (int i = 0; i < 4; ++i) {
      a[i] = *(short8*)&As[wm + i * 16 + r][g * 8];
      b[i] = *(short8*)&Bs[wn + i * 16 + r][g * 8];
    }
#pragma unroll
    for (int i = 0; i < 4; ++i)
#pragma unroll
      for (int j = 0; j < 4; ++j)
        acc[i][j] = mfma16(a[i], b[j], acc[i][j]);
    __syncthreads();
  }
#pragma unroll
  for (int i = 0; i < 4; ++i)
#pragma unroll
    for (int j = 0; j < 4; ++j)
#pragma unroll
      for (int reg = 0; reg < 4; ++reg) {
        int m = mbase + wm + i * 16 + g * 4 + reg;
        int n = nbase + wn + j * 16 + r;
        int b_ = m >> 11, s = m & 2047, h = n >> 6, d = n & 63;
        if (which == 0) {
          short v = f2bf(acc[i][j][reg] * 0.18033688f); // 1/8 * log2(e)
          Qo[(((size_t)b_ * NH + h) * S_LEN + s) * DK + d] = v;
        } else if (which == 1) {
          short v = f2bf(acc[i][j][reg]);
          Ko[(((size_t)b_ * NH + h) * S_LEN + s) * DK + (d ^ ((s & 7) << 3))] = v;
        } else {
          short v = f2bf(acc[i][j][reg]);
          Vo[(((size_t)b_ * NH + h) * DK + d) * S_LEN + (s ^ ((d & 7) << 3))] = v;
        }
      }
}

// ---------------------------------------------------------------------------
// 3) Flash attention, split-KV=2: grid (32 qtiles, 24 bh, 2 splits).
//    Inner loop is round-4-exact (it passed). Each split writes NORMALIZED
//    partials v_s = o_s/l_s (bf16) + (m_s, l_s) f32; merge interpolates.
// ---------------------------------------------------------------------------
__global__ __launch_bounds__(128) void attn_kernel(
    const short* __restrict__ Qg, const short* __restrict__ Kg,
    const short* __restrict__ Vt, short* __restrict__ oP,
    float* __restrict__ mlP) {
  __shared__ char K_lds[2][8192];
  __shared__ char V_lds[2][8192];
  int bh = blockIdx.y;
  int split = blockIdx.z;
  int tid = threadIdx.x;
  int w = tid >> 6, lane = tid & 63;
  int c32 = lane & 31, hi = lane >> 5;
  int qbase = blockIdx.x * 64 + w * 32;
  int kc0 = split * (S_LEN / 2);
  const short* qp = Qg + (size_t)bh * S_LEN * DK;
  const char* kp = (const char*)(Kg + (size_t)bh * S_LEN * DK);
  const char* vp = (const char*)(Vt + (size_t)bh * DK * S_LEN);

  short8 qf[4];
#pragma unroll
  for (int kk = 0; kk < 4; ++kk)
    qf[kk] = *(const short8*)(qp + (size_t)(qbase + c32) * DK + kk * 16 + hi * 8);

#define STAGE(buf, kc)                                                          \
  {                                                                             \
    _Pragma("unroll") for (int j = 0; j < 4; ++j) {                             \
      int p = w * 4 + j;                                                        \
      gl16(kp + (size_t)(kc)*128 + p * 1024 + lane * 16, &K_lds[buf][p * 1024]);\
    }                                                                           \
    _Pragma("unroll") for (int j = 0; j < 4; ++j) {                             \
      int p = w * 4 + j;                                                        \
      int row = p * 8 + (lane >> 3);                                            \
      gl16(vp + (size_t)row * 4096 + (kc)*2 + (lane & 7) * 16,                  \
           &V_lds[buf][p * 1024]);                                              \
    }                                                                           \
  }

  STAGE(0, kc0);

  f32x16 o0 = {}, o1 = {};
  float m_run = -30000.f, l_run = 0.f;
  int cur = 0;
  const int NT = (S_LEN / 2) / 64; // 16

  for (int t = 0; t < NT; ++t) {
    if (t < NT - 1) {
      STAGE(cur ^ 1, kc0 + (t + 1) * 64);
      asm volatile("s_waitcnt vmcnt(8)" ::: "memory");
    } else {
      asm volatile("s_waitcnt vmcnt(0)" ::: "memory");
    }
    __builtin_amdgcn_s_barrier();

    const char* kb = K_lds[cur];
    const char* vb = V_lds[cur];

    f32x16 st0 = {}, st1 = {};
#pragma unroll
    for (int kk = 0; kk < 4; ++kk) {
      int cb = kk * 32 + hi * 16;
      short8 k0 = *(const short8*)(kb + c32 * 128 + (cb ^ ((c32 & 7) << 4)));
      short8 k1 = *(const short8*)(kb + (32 + c32) * 128 + (cb ^ ((c32 & 7) << 4)));
      st0 = mfma32(k0, qf[kk], st0);
      st1 = mfma32(k1, qf[kk], st1);
    }

    float cm = -30000.f;
#pragma unroll
    for (int i = 0; i < 16; ++i) cm = fmaxf(cm, fmaxf(st0[i], st1[i]));
    cm = fmaxf(cm, __shfl_xor(cm, 32));
    if (!__all(cm <= m_run + 8.0f)) {
      float m_new = fmaxf(m_run, cm);
      float al = __builtin_amdgcn_exp2f(m_run - m_new);
      l_run *= al;
      m_run = m_new;
#pragma unroll
      for (int r = 0; r < 16; ++r) {
        int ql = (r & 3) + 8 * (r >> 2) + 4 * hi;
        float ar = __shfl(al, ql);
        o0[r] *= ar;
        o1[r] *= ar;
      }
    }
    float csum = 0.f;
#pragma unroll
    for (int i = 0; i < 16; ++i) {
      st0[i] = __builtin_amdgcn_exp2f(st0[i] - m_run);
      st1[i] = __builtin_amdgcn_exp2f(st1[i] - m_run);
      csum += st0[i] + st1[i];
    }
    csum += __shfl_xor(csum, 32);
    l_run += csum;

#pragma unroll
    for (int ks = 0; ks < 4; ++ks) {
      f32x16 P = (ks < 2) ? st0 : st1;
      int s8 = (ks & 1) * 8;
      unsigned A = cvtpk(P[s8 + 0], P[s8 + 1]);
      unsigned Bx = cvtpk(P[s8 + 4], P[s8 + 5]);
      unsigned C = cvtpk(P[s8 + 2], P[s8 + 3]);
      unsigned Dx = cvtpk(P[s8 + 6], P[s8 + 7]);
      plswap(A, Bx);
      plswap(C, Dx);
      union { unsigned u[4]; short8 s; } pu;
      pu.u[0] = A; pu.u[1] = C; pu.u[2] = Bx; pu.u[3] = Dx;
      int cb = ks * 32 + hi * 16;
      short8 v0 = *(const short8*)(vb + c32 * 128 + (cb ^ ((c32 & 7) << 4)));
      short8 v1 = *(const short8*)(vb + (32 + c32) * 128 + (cb ^ ((c32 & 7) << 4)));
      o0 = mfma32(pu.s, v0, o0);
      o1 = mfma32(pu.s, v1, o1);
    }

    __builtin_amdgcn_s_barrier();
    cur ^= 1;
  }

  // epilogue: write NORMALIZED partial (round-4-exact math) + (m,l)
  size_t pbase = ((size_t)split * 24 + bh) * S_LEN;
#pragma unroll
  for (int r = 0; r < 16; ++r) {
    int ql = (r & 3) + 8 * (r >> 2) + 4 * hi;
    float linv = 1.0f / __shfl(l_run, ql);
    short* op = oP + (pbase + qbase + ql) * DK;
    op[c32] = f2bf(o0[r] * linv);
    op[32 + c32] = f2bf(o1[r] * linv);
  }
  if (hi == 0) {
    float* mlp = mlP + (pbase + qbase + c32) * 2;
    mlp[0] = m_run;
    mlp[1] = l_run;
  }
#undef STAGE
}

// ---------------------------------------------------------------------------
// 3b) Merge split-KV partials -> ctx. Pure interpolation of normalized v_s:
//     a_s = l_s * 2^(m_s - m);  v = (v0*a0 + v1*a1) / (a0 + a1)
// ---------------------------------------------------------------------------
__global__ __launch_bounds__(256) void merge_kernel(
    const short* __restrict__ oP, const float* __restrict__ mlP,
    short* __restrict__ Cx) {
  int t = blockIdx.x * 256 + threadIdx.x;
  int q = t >> 5, dp = (t & 31) * 2;
  const int NQ = 24 * S_LEN;
  float2 ml0 = *(const float2*)(mlP + (size_t)q * 2);
  float2 ml1 = *(const float2*)(mlP + ((size_t)NQ + q) * 2);
  float m = fmaxf(ml0.x, ml1.x);
  float a0 = ml0.y * __builtin_amdgcn_exp2f(ml0.x - m);
  float a1 = ml1.y * __builtin_amdgcn_exp2f(ml1.x - m);
  float inv = 1.0f / (a0 + a1);
  float w0 = a0 * inv, w1 = a1 * inv;
  uint32_t a = *(const uint32_t*)(oP + (size_t)q * DK + dp);
  uint32_t b2 = *(const uint32_t*)(oP + ((size_t)NQ + q) * DK + dp);
  float v0 = lo16(a) * w0 + lo16(b2) * w1;
  float v1 = hi16(a) * w0 + hi16(b2) * w1;
  int bh = q >> 11, sr = q & 2047, b = bh / NH, h = bh % NH;
  uint32_t outw = (uint32_t)(uint16_t)f2bf(v0) | ((uint32_t)(uint16_t)f2bf(v1) << 16);
  *(uint32_t*)(Cx + ((size_t)(b * S_LEN + sr)) * D_MODEL + h * DK + dp) = outw;
}

// ---------------------------------------------------------------------------
// 4a) Y = ctx @ Wo + resid  (f32 out). Same 128x128 m97 structure as proj.
// ---------------------------------------------------------------------------
__global__ __launch_bounds__(256) void gemm_out_kernel(
    const short* __restrict__ ctx, const short* __restrict__ WoT,
    const float* __restrict__ resid, float* __restrict__ Y) {
  int bid = blockIdx.x;
  int wk = (bid & 7) * 24 + (bid >> 3);   // 192 % 8 == 0 -> bijective
  int mt = wk / 6, nt = wk % 6;
  int mbase = mt * 128, nbase = nt * 128;

  __shared__ short As[128][32];
  __shared__ short Bs[128][32];
  int tid = threadIdx.x;
  int wv = tid >> 6, lane = tid & 63, r = lane & 15, g = lane >> 4;
  int wm = (wv & 1) * 64, wn = (wv >> 1) * 64;
  int srow = (lane >> 2), scol = (lane & 3) * 8;

  f32x4 acc[4][4] = {};
  for (int kk = 0; kk < D_MODEL; kk += 32) {
#pragma unroll
    for (int j = 0; j < 2; ++j) {
      int row = wv * 32 + j * 16;
      gl16(ctx + (size_t)(mbase + row + srow) * D_MODEL + kk + scol, &As[row][0]);
      gl16(WoT + (size_t)(nbase + row + srow) * D_MODEL + kk + scol, &Bs[row][0]);
    }
    __syncthreads();
    short8 a[4], b[4];
#pragma unroll
    for (int i = 0; i < 4; ++i) {
      a[i] = *(short8*)&As[wm + i * 16 + r][g * 8];
      b[i] = *(short8*)&Bs[wn + i * 16 + r][g * 8];
    }
#pragma unroll
    for (int i = 0; i < 4; ++i)
#pragma unroll
      for (int j = 0; j < 4; ++j)
        acc[i][j] = mfma16(a[i], b[j], acc[i][j]);
    __syncthreads();
  }
#pragma unroll
  for (int i = 0; i < 4; ++i)
#pragma unroll
    for (int j = 0; j < 4; ++j)
#pragma unroll
      for (int reg = 0; reg < 4; ++reg) {
        int m = mbase + wm + i * 16 + g * 4 + reg;
        int n = nbase + wn + j * 16 + r;
        Y[(size_t)m * D_MODEL + n] = acc[i][j][reg] + resid[(size_t)m * D_MODEL + n];
      }
}

// ---------------------------------------------------------------------------
// 4b) LayerNorm over Y rows (wave per row). Y already includes residual.
// ---------------------------------------------------------------------------
__global__ __launch_bounds__(256) void ln_kernel(const float* __restrict__ Y,
                                                 float* __restrict__ out) {
  int row = blockIdx.x * 4 + (threadIdx.x >> 6);
  int l = threadIdx.x & 63;
  const float* yp = Y + (size_t)row * D_MODEL;
  float v[12];
  float s = 0.f, q = 0.f;
#pragma unroll
  for (int c = 0; c < 12; ++c) {
    v[c] = yp[c * 64 + l];
    s += v[c];
    q += v[c] * v[c];
  }
#pragma unroll
  for (int d = 1; d < 64; d <<= 1) {
    s += __shfl_xor(s, d);
    q += __shfl_xor(q, d);
  }
  float mu = s * (1.0f / 768.0f);
  float var = q * (1.0f / 768.0f) - mu * mu;
  float rstd = rsqrtf(var + 1e-5f);
  float* op = out + (size_t)row * D_MODEL;
#pragma unroll
  for (int c = 0; c < 12; ++c)
    op[c * 64 + l] = (v[c] - mu) * rstd;
}

// ---------------------------------------------------------------------------
extern "C" void kernel_launch(void* const* d_in, const int* in_sizes, int n_in,
                              void* d_out, int out_size, void* d_ws, size_t ws_size,
                              hipStream_t stream) {
  const float* xq = (const float*)d_in[0];
  const float* xk = (const float*)d_in[1];
  const float* xv = (const float*)d_in[2];
  const float* Wq = (const float*)d_in[3];
  const float* Wk = (const float*)d_in[4];
  const float* Wv = (const float*)d_in[5];
  const float* Wo = (const float*)d_in[6];
  float* out = (float*)d_out;

  char* ws = (char*)d_ws;
  const size_t WSZ = (size_t)D_MODEL * D_MODEL;   // 589824
  const size_t QSZ = (size_t)M_TOT * D_MODEL;     // 3145728
  short* WT = (short*)ws;                         // 4 * WSZ
  short* Xb = WT + 4 * WSZ;                       // 3 * QSZ (bf16 activations)
  short* Qb = Xb + 3 * QSZ;
  short* Kb = Qb + QSZ;
  short* Vb = Kb + QSZ;
  short* Cx = Vb + QSZ;
  // aliases into dead Xb region (Xb consumed by proj before attn writes):
  short* oP = Xb;                                          // 12.6 MB
  float* mlP = (float*)(Xb + (size_t)2 * 24 * S_LEN * DK); // 786 KB
  float* Yf = (float*)Xb;  // used after merge consumed partials

  transpose_w_kernel<<<dim3(24, 24, 4), dim3(32, 8), 0, stream>>>(Wq, Wk, Wv, Wo, WT);
  cast_x_kernel<<<dim3(1536, 3), 256, 0, stream>>>(xq, xk, xv, Xb);
  proj_kernel<<<576, 256, 0, stream>>>(Xb, WT, Qb, Kb, Vb);
  attn_kernel<<<dim3(32, 24, 2), 128, 0, stream>>>(Qb, Kb, Vb, oP, mlP);
  merge_kernel<<<6144, 256, 0, stream>>>(oP, mlP, Cx);
  gemm_out_kernel<<<192, 256, 0, stream>>>(Cx, WT + 3 * WSZ, xq, Yf);
  ln_kernel<<<1024, 256, 0, stream>>>(Yf, out);
}

// Round 7
// 223.693 us; speedup vs baseline: 1.0430x; 1.0430x over previous
//
#include <hip/hip_runtime.h>
#include <hip/hip_bf16.h>
#include <stdint.h>

#define S_LEN 2048
#define D_MODEL 768
#define NH 12
#define DK 64
#define BATCH 2
#define M_TOT (BATCH * S_LEN) /* 4096 */

typedef __attribute__((ext_vector_type(8))) short short8;
typedef __attribute__((ext_vector_type(4))) float f32x4;
typedef __attribute__((ext_vector_type(16))) float f32x16;

__device__ inline short f2bf(float f) {
  union { float f; uint32_t u; } v; v.f = f;
  uint32_t r = v.u + 0x7fffu + ((v.u >> 16) & 1u);
  return (short)(r >> 16);
}

__device__ inline f32x4 mfma16(short8 a, short8 b, f32x4 c) {
  return __builtin_amdgcn_mfma_f32_16x16x32_bf16(a, b, c, 0, 0, 0);
}
__device__ inline f32x16 mfma32(short8 a, short8 b, f32x16 c) {
  return __builtin_amdgcn_mfma_f32_32x32x16_bf16(a, b, c, 0, 0, 0);
}

__device__ inline void gl16(const void* g, void* l) {
  __builtin_amdgcn_global_load_lds(
      (const __attribute__((address_space(1))) unsigned*)g,
      (__attribute__((address_space(3))) unsigned*)l, 16, 0, 0);
}

__device__ inline unsigned cvtpk(float lo, float hi) {
  unsigned r;
  asm("v_cvt_pk_bf16_f32 %0, %1, %2" : "=v"(r) : "v"(lo), "v"(hi));
  return r;
}
__device__ inline void plswap(unsigned& a, unsigned& b) {
  asm("v_permlane32_swap_b32 %0, %1" : "+v"(a), "+v"(b));
}
__device__ inline float lo16(uint32_t u) {
  union { uint32_t u; float f; } x; x.u = u << 16; return x.f;
}
__device__ inline float hi16(uint32_t u) {
  union { uint32_t u; float f; } x; x.u = u & 0xffff0000u; return x.f;
}

// ---------------------------------------------------------------------------
// 1a) Weight transpose + bf16 cast (all 4 weights in one launch, z selects)
// ---------------------------------------------------------------------------
__global__ __launch_bounds__(256) void transpose_w_kernel(
    const float* __restrict__ Wq, const float* __restrict__ Wk,
    const float* __restrict__ Wv, const float* __restrict__ Wo,
    short* __restrict__ WT) {
  int z = blockIdx.z;
  const float* W = z == 0 ? Wq : (z == 1 ? Wk : (z == 2 ? Wv : Wo));
  short* O = WT + (size_t)z * D_MODEL * D_MODEL;
  __shared__ float t[32][33];
  int x = threadIdx.x, y = threadIdx.y;
  int nb = blockIdx.x * 32, kb = blockIdx.y * 32;
#pragma unroll
  for (int j = 0; j < 4; ++j)
    t[y + 8 * j][x] = W[(kb + y + 8 * j) * D_MODEL + nb + x];
  __syncthreads();
#pragma unroll
  for (int j = 0; j < 4; ++j)
    O[(nb + y + 8 * j) * D_MODEL + kb + x] = f2bf(t[x][y + 8 * j]);
}

// ---------------------------------------------------------------------------
// 1b) Activation cast fp32 -> bf16
// ---------------------------------------------------------------------------
__global__ __launch_bounds__(256) void cast_x_kernel(
    const float* __restrict__ Xq, const float* __restrict__ Xk,
    const float* __restrict__ Xv, short* __restrict__ Xb) {
  int z = blockIdx.y;
  const float* X = z == 0 ? Xq : (z == 1 ? Xk : Xv);
  short* O = Xb + (size_t)z * M_TOT * D_MODEL;
  size_t i = ((size_t)blockIdx.x * 256 + threadIdx.x) * 8;
  float4 f0 = *(const float4*)(X + i);
  float4 f1 = *(const float4*)(X + i + 4);
  short8 v;
  v[0] = f2bf(f0.x); v[1] = f2bf(f0.y); v[2] = f2bf(f0.z); v[3] = f2bf(f0.w);
  v[4] = f2bf(f1.x); v[5] = f2bf(f1.y); v[6] = f2bf(f1.z); v[7] = f2bf(f1.w);
  *(short8*)(O + i) = v;
}

// ---------------------------------------------------------------------------
// 2) Projections, m97-style 128x128 tile, BK=32, global_load_lds staging.
// ---------------------------------------------------------------------------
__global__ __launch_bounds__(256) void proj_kernel(
    const short* __restrict__ Xb, const short* __restrict__ WTall,
    short* __restrict__ Qo, short* __restrict__ Ko, short* __restrict__ Vo) {
  int bid = blockIdx.x;
  int wk = (bid & 7) * 72 + (bid >> 3);   // 576 % 8 == 0 -> bijective
  int which = wk / 192;
  int rem = wk % 192;
  int mt = rem / 6, nt = rem % 6;
  int mbase = mt * 128, nbase = nt * 128;
  const short* X = Xb + (size_t)which * M_TOT * D_MODEL;
  const short* WT = WTall + (size_t)which * D_MODEL * D_MODEL;

  __shared__ short As[128][32];
  __shared__ short Bs[128][32];
  int tid = threadIdx.x;
  int wv = tid >> 6, lane = tid & 63, r = lane & 15, g = lane >> 4;
  int wm = (wv & 1) * 64, wn = (wv >> 1) * 64;
  int srow = (lane >> 2), scol = (lane & 3) * 8;

  f32x4 acc[4][4] = {};
  for (int kk = 0; kk < D_MODEL; kk += 32) {
#pragma unroll
    for (int j = 0; j < 2; ++j) {
      int row = wv * 32 + j * 16;
      gl16(X + (size_t)(mbase + row + srow) * D_MODEL + kk + scol, &As[row][0]);
      gl16(WT + (size_t)(nbase + row + srow) * D_MODEL + kk + scol, &Bs[row][0]);
    }
    __syncthreads();
    short8 a[4], b[4];
#pragma unroll
    for (int i = 0; i < 4; ++i) {
      a[i] = *(short8*)&As[wm + i * 16 + r][g * 8];
      b[i] = *(short8*)&Bs[wn + i * 16 + r][g * 8];
    }
#pragma unroll
    for (int i = 0; i < 4; ++i)
#pragma unroll
      for (int j = 0; j < 4; ++j)
        acc[i][j] = mfma16(a[i], b[j], acc[i][j]);
    __syncthreads();
  }
#pragma unroll
  for (int i = 0; i < 4; ++i)
#pragma unroll
    for (int j = 0; j < 4; ++j)
#pragma unroll
      for (int reg = 0; reg < 4; ++reg) {
        int m = mbase + wm + i * 16 + g * 4 + reg;
        int n = nbase + wn + j * 16 + r;
        int b_ = m >> 11, s = m & 2047, h = n >> 6, d = n & 63;
        if (which == 0) {
          short v = f2bf(acc[i][j][reg] * 0.18033688f); // 1/8 * log2(e)
          Qo[(((size_t)b_ * NH + h) * S_LEN + s) * DK + d] = v;
        } else if (which == 1) {
          short v = f2bf(acc[i][j][reg]);
          Ko[(((size_t)b_ * NH + h) * S_LEN + s) * DK + (d ^ ((s & 7) << 3))] = v;
        } else {
          short v = f2bf(acc[i][j][reg]);
          Vo[(((size_t)b_ * NH + h) * DK + d) * S_LEN + (s ^ ((d & 7) << 3))] = v;
        }
      }
}

// ---------------------------------------------------------------------------
// 3) Flash attention, NO-LDS variant: K/V read directly from global (L2-hot,
//    same swizzled layouts). No barriers, no staging -> occupancy VGPR-bound.
//    4 waves/block x 32 q-rows, split-KV=2, normalized partials + merge.
// ---------------------------------------------------------------------------
__global__ __launch_bounds__(256) void attn_kernel(
    const short* __restrict__ Qg, const short* __restrict__ Kg,
    const short* __restrict__ Vt, short* __restrict__ oP,
    float* __restrict__ mlP) {
  int bh = blockIdx.y;
  int split = blockIdx.z;
  int tid = threadIdx.x;
  int w = tid >> 6, lane = tid & 63;
  int c32 = lane & 31, hi = lane >> 5;
  int qbase = blockIdx.x * 128 + w * 32;
  int kc0 = split * (S_LEN / 2);
  const short* qp = Qg + (size_t)bh * S_LEN * DK;
  const char* kp = (const char*)(Kg + (size_t)bh * S_LEN * DK);
  const char* vp = (const char*)(Vt + (size_t)bh * DK * S_LEN);

  short8 qf[4];
#pragma unroll
  for (int kk = 0; kk < 4; ++kk)
    qf[kk] = *(const short8*)(qp + (size_t)(qbase + c32) * DK + kk * 16 + hi * 8);

  f32x16 o0 = {}, o1 = {};
  float m_run = -30000.f, l_run = 0.f;
  const int NT = (S_LEN / 2) / 64; // 16
  int sw = (c32 & 7) << 4;

  for (int t = 0; t < NT; ++t) {
    int kc = kc0 + t * 64;
    const char* kt = kp + (size_t)kc * 128; // K rows kc..kc+63 (128B each)
    const char* vt = vp + (size_t)kc * 2;   // V cols at byte kc*2, row stride 4096

    // QK^T: fragments straight from global (L2-hot)
    f32x16 st0 = {}, st1 = {};
#pragma unroll
    for (int kk = 0; kk < 4; ++kk) {
      int cb = kk * 32 + hi * 16;
      short8 k0 = *(const short8*)(kt + (size_t)c32 * 128 + (cb ^ sw));
      short8 k1 = *(const short8*)(kt + (size_t)(32 + c32) * 128 + (cb ^ sw));
      st0 = mfma32(k0, qf[kk], st0);
      st1 = mfma32(k1, qf[kk], st1);
    }

    // V fragment loads issued early; consumed after softmax (~400cy later)
    short8 vl0[4], vl1[4];
#pragma unroll
    for (int ks = 0; ks < 4; ++ks) {
      int cb = ks * 32 + hi * 16;
      vl0[ks] = *(const short8*)(vt + (size_t)c32 * 4096 + (cb ^ sw));
      vl1[ks] = *(const short8*)(vt + (size_t)(32 + c32) * 4096 + (cb ^ sw));
    }

    float cm = -30000.f;
#pragma unroll
    for (int i = 0; i < 16; ++i) cm = fmaxf(cm, fmaxf(st0[i], st1[i]));
    cm = fmaxf(cm, __shfl_xor(cm, 32));
    if (!__all(cm <= m_run + 8.0f)) {
      float m_new = fmaxf(m_run, cm);
      float al = __builtin_amdgcn_exp2f(m_run - m_new);
      l_run *= al;
      m_run = m_new;
#pragma unroll
      for (int r = 0; r < 16; ++r) {
        int ql = (r & 3) + 8 * (r >> 2) + 4 * hi;
        float ar = __shfl(al, ql);
        o0[r] *= ar;
        o1[r] *= ar;
      }
    }
    float csum = 0.f;
#pragma unroll
    for (int i = 0; i < 16; ++i) {
      st0[i] = __builtin_amdgcn_exp2f(st0[i] - m_run);
      st1[i] = __builtin_amdgcn_exp2f(st1[i] - m_run);
      csum += st0[i] + st1[i];
    }
    csum += __shfl_xor(csum, 32);
    l_run += csum;

#pragma unroll
    for (int ks = 0; ks < 4; ++ks) {
      f32x16 P = (ks < 2) ? st0 : st1;
      int s8 = (ks & 1) * 8;
      unsigned A = cvtpk(P[s8 + 0], P[s8 + 1]);
      unsigned Bx = cvtpk(P[s8 + 4], P[s8 + 5]);
      unsigned C = cvtpk(P[s8 + 2], P[s8 + 3]);
      unsigned Dx = cvtpk(P[s8 + 6], P[s8 + 7]);
      plswap(A, Bx);
      plswap(C, Dx);
      union { unsigned u[4]; short8 s; } pu;
      pu.u[0] = A; pu.u[1] = C; pu.u[2] = Bx; pu.u[3] = Dx;
      o0 = mfma32(pu.s, vl0[ks], o0);
      o1 = mfma32(pu.s, vl1[ks], o1);
    }
  }

  // epilogue: write NORMALIZED partial + (m,l)
  size_t pbase = ((size_t)split * 24 + bh) * S_LEN;
#pragma unroll
  for (int r = 0; r < 16; ++r) {
    int ql = (r & 3) + 8 * (r >> 2) + 4 * hi;
    float linv = 1.0f / __shfl(l_run, ql);
    short* op = oP + (pbase + qbase + ql) * DK;
    op[c32] = f2bf(o0[r] * linv);
    op[32 + c32] = f2bf(o1[r] * linv);
  }
  if (hi == 0) {
    float* mlp = mlP + (pbase + qbase + c32) * 2;
    mlp[0] = m_run;
    mlp[1] = l_run;
  }
}

// ---------------------------------------------------------------------------
// 3b) Merge split-KV partials -> ctx. Pure interpolation of normalized v_s:
//     a_s = l_s * 2^(m_s - m);  v = (v0*a0 + v1*a1) / (a0 + a1)
// ---------------------------------------------------------------------------
__global__ __launch_bounds__(256) void merge_kernel(
    const short* __restrict__ oP, const float* __restrict__ mlP,
    short* __restrict__ Cx) {
  int t = blockIdx.x * 256 + threadIdx.x;
  int q = t >> 5, dp = (t & 31) * 2;
  const int NQ = 24 * S_LEN;
  float2 ml0 = *(const float2*)(mlP + (size_t)q * 2);
  float2 ml1 = *(const float2*)(mlP + ((size_t)NQ + q) * 2);
  float m = fmaxf(ml0.x, ml1.x);
  float a0 = ml0.y * __builtin_amdgcn_exp2f(ml0.x - m);
  float a1 = ml1.y * __builtin_amdgcn_exp2f(ml1.x - m);
  float inv = 1.0f / (a0 + a1);
  float w0 = a0 * inv, w1 = a1 * inv;
  uint32_t a = *(const uint32_t*)(oP + (size_t)q * DK + dp);
  uint32_t b2 = *(const uint32_t*)(oP + ((size_t)NQ + q) * DK + dp);
  float v0 = lo16(a) * w0 + lo16(b2) * w1;
  float v1 = hi16(a) * w0 + hi16(b2) * w1;
  int bh = q >> 11, sr = q & 2047, b = bh / NH, h = bh % NH;
  uint32_t outw = (uint32_t)(uint16_t)f2bf(v0) | ((uint32_t)(uint16_t)f2bf(v1) << 16);
  *(uint32_t*)(Cx + ((size_t)(b * S_LEN + sr)) * D_MODEL + h * DK + dp) = outw;
}

// ---------------------------------------------------------------------------
// 4a) Y = ctx @ Wo + resid  (f32 out). Same 128x128 m97 structure as proj.
// ---------------------------------------------------------------------------
__global__ __launch_bounds__(256) void gemm_out_kernel(
    const short* __restrict__ ctx, const short* __restrict__ WoT,
    const float* __restrict__ resid, float* __restrict__ Y) {
  int bid = blockIdx.x;
  int wk = (bid & 7) * 24 + (bid >> 3);   // 192 % 8 == 0 -> bijective
  int mt = wk / 6, nt = wk % 6;
  int mbase = mt * 128, nbase = nt * 128;

  __shared__ short As[128][32];
  __shared__ short Bs[128][32];
  int tid = threadIdx.x;
  int wv = tid >> 6, lane = tid & 63, r = lane & 15, g = lane >> 4;
  int wm = (wv & 1) * 64, wn = (wv >> 1) * 64;
  int srow = (lane >> 2), scol = (lane & 3) * 8;

  f32x4 acc[4][4] = {};
  for (int kk = 0; kk < D_MODEL; kk += 32) {
#pragma unroll
    for (int j = 0; j < 2; ++j) {
      int row = wv * 32 + j * 16;
      gl16(ctx + (size_t)(mbase + row + srow) * D_MODEL + kk + scol, &As[row][0]);
      gl16(WoT + (size_t)(nbase + row + srow) * D_MODEL + kk + scol, &Bs[row][0]);
    }
    __syncthreads();
    short8 a[4], b[4];
#pragma unroll
    for (int i = 0; i < 4; ++i) {
      a[i] = *(short8*)&As[wm + i * 16 + r][g * 8];
      b[i] = *(short8*)&Bs[wn + i * 16 + r][g * 8];
    }
#pragma unroll
    for (int i = 0; i < 4; ++i)
#pragma unroll
      for (int j = 0; j < 4; ++j)
        acc[i][j] = mfma16(a[i], b[j], acc[i][j]);
    __syncthreads();
  }
#pragma unroll
  for (int i = 0; i < 4; ++i)
#pragma unroll
    for (int j = 0; j < 4; ++j)
#pragma unroll
      for (int reg = 0; reg < 4; ++reg) {
        int m = mbase + wm + i * 16 + g * 4 + reg;
        int n = nbase + wn + j * 16 + r;
        Y[(size_t)m * D_MODEL + n] = acc[i][j][reg] + resid[(size_t)m * D_MODEL + n];
      }
}

// ---------------------------------------------------------------------------
// 4b) LayerNorm over Y rows (wave per row). Y already includes residual.
// ---------------------------------------------------------------------------
__global__ __launch_bounds__(256) void ln_kernel(const float* __restrict__ Y,
                                                 float* __restrict__ out) {
  int row = blockIdx.x * 4 + (threadIdx.x >> 6);
  int l = threadIdx.x & 63;
  const float* yp = Y + (size_t)row * D_MODEL;
  float v[12];
  float s = 0.f, q = 0.f;
#pragma unroll
  for (int c = 0; c < 12; ++c) {
    v[c] = yp[c * 64 + l];
    s += v[c];
    q += v[c] * v[c];
  }
#pragma unroll
  for (int d = 1; d < 64; d <<= 1) {
    s += __shfl_xor(s, d);
    q += __shfl_xor(q, d);
  }
  float mu = s * (1.0f / 768.0f);
  float var = q * (1.0f / 768.0f) - mu * mu;
  float rstd = rsqrtf(var + 1e-5f);
  float* op = out + (size_t)row * D_MODEL;
#pragma unroll
  for (int c = 0; c < 12; ++c)
    op[c * 64 + l] = (v[c] - mu) * rstd;
}

// ---------------------------------------------------------------------------
extern "C" void kernel_launch(void* const* d_in, const int* in_sizes, int n_in,
                              void* d_out, int out_size, void* d_ws, size_t ws_size,
                              hipStream_t stream) {
  const float* xq = (const float*)d_in[0];
  const float* xk = (const float*)d_in[1];
  const float* xv = (const float*)d_in[2];
  const float* Wq = (const float*)d_in[3];
  const float* Wk = (const float*)d_in[4];
  const float* Wv = (const float*)d_in[5];
  const float* Wo = (const float*)d_in[6];
  float* out = (float*)d_out;

  char* ws = (char*)d_ws;
  const size_t WSZ = (size_t)D_MODEL * D_MODEL;   // 589824
  const size_t QSZ = (size_t)M_TOT * D_MODEL;     // 3145728
  short* WT = (short*)ws;                         // 4 * WSZ
  short* Xb = WT + 4 * WSZ;                       // 3 * QSZ (bf16 activations)
  short* Qb = Xb + 3 * QSZ;
  short* Kb = Qb + QSZ;
  short* Vb = Kb + QSZ;
  short* Cx = Vb + QSZ;
  // aliases into dead Xb region (Xb consumed by proj before attn writes):
  short* oP = Xb;                                          // 12.6 MB
  float* mlP = (float*)(Xb + (size_t)2 * 24 * S_LEN * DK); // 786 KB
  float* Yf = (float*)Xb;  // used after merge consumed partials

  transpose_w_kernel<<<dim3(24, 24, 4), dim3(32, 8), 0, stream>>>(Wq, Wk, Wv, Wo, WT);
  cast_x_kernel<<<dim3(1536, 3), 256, 0, stream>>>(xq, xk, xv, Xb);
  proj_kernel<<<576, 256, 0, stream>>>(Xb, WT, Qb, Kb, Vb);
  attn_kernel<<<dim3(16, 24, 2), 256, 0, stream>>>(Qb, Kb, Vb, oP, mlP);
  merge_kernel<<<6144, 256, 0, stream>>>(oP, mlP, Cx);
  gemm_out_kernel<<<192, 256, 0, stream>>>(Cx, WT + 3 * WSZ, xq, Yf);
  ln_kernel<<<1024, 256, 0, stream>>>(Yf, out);
}

// Round 8
// 219.015 us; speedup vs baseline: 1.0653x; 1.0214x over previous
//
#include <hip/hip_runtime.h>
#include <hip/hip_bf16.h>
#include <stdint.h>

#define S_LEN 2048
#define D_MODEL 768
#define NH 12
#define DK 64
#define BATCH 2
#define M_TOT (BATCH * S_LEN) /* 4096 */

typedef __attribute__((ext_vector_type(8))) short short8;
typedef __attribute__((ext_vector_type(4))) float f32x4;
typedef __attribute__((ext_vector_type(16))) float f32x16;

__device__ inline short f2bf(float f) {
  union { float f; uint32_t u; } v; v.f = f;
  uint32_t r = v.u + 0x7fffu + ((v.u >> 16) & 1u);
  return (short)(r >> 16);
}

__device__ inline f32x4 mfma16(short8 a, short8 b, f32x4 c) {
  return __builtin_amdgcn_mfma_f32_16x16x32_bf16(a, b, c, 0, 0, 0);
}
__device__ inline f32x16 mfma32(short8 a, short8 b, f32x16 c) {
  return __builtin_amdgcn_mfma_f32_32x32x16_bf16(a, b, c, 0, 0, 0);
}

__device__ inline void gl16(const void* g, void* l) {
  __builtin_amdgcn_global_load_lds(
      (const __attribute__((address_space(1))) unsigned*)g,
      (__attribute__((address_space(3))) unsigned*)l, 16, 0, 0);
}

__device__ inline unsigned cvtpk(float lo, float hi) {
  unsigned r;
  asm("v_cvt_pk_bf16_f32 %0, %1, %2" : "=v"(r) : "v"(lo), "v"(hi));
  return r;
}
__device__ inline void plswap(unsigned& a, unsigned& b) {
  asm("v_permlane32_swap_b32 %0, %1" : "+v"(a), "+v"(b));
}
__device__ inline float lo16(uint32_t u) {
  union { uint32_t u; float f; } x; x.u = u << 16; return x.f;
}
__device__ inline float hi16(uint32_t u) {
  union { uint32_t u; float f; } x; x.u = u & 0xffff0000u; return x.f;
}

// ---------------------------------------------------------------------------
// 1a) Weight transpose + bf16 cast (all 4 weights in one launch, z selects)
// ---------------------------------------------------------------------------
__global__ __launch_bounds__(256) void transpose_w_kernel(
    const float* __restrict__ Wq, const float* __restrict__ Wk,
    const float* __restrict__ Wv, const float* __restrict__ Wo,
    short* __restrict__ WT) {
  int z = blockIdx.z;
  const float* W = z == 0 ? Wq : (z == 1 ? Wk : (z == 2 ? Wv : Wo));
  short* O = WT + (size_t)z * D_MODEL * D_MODEL;
  __shared__ float t[32][33];
  int x = threadIdx.x, y = threadIdx.y;
  int nb = blockIdx.x * 32, kb = blockIdx.y * 32;
#pragma unroll
  for (int j = 0; j < 4; ++j)
    t[y + 8 * j][x] = W[(kb + y + 8 * j) * D_MODEL + nb + x];
  __syncthreads();
#pragma unroll
  for (int j = 0; j < 4; ++j)
    O[(nb + y + 8 * j) * D_MODEL + kb + x] = f2bf(t[x][y + 8 * j]);
}

// ---------------------------------------------------------------------------
// 1b) Activation cast fp32 -> bf16
// ---------------------------------------------------------------------------
__global__ __launch_bounds__(256) void cast_x_kernel(
    const float* __restrict__ Xq, const float* __restrict__ Xk,
    const float* __restrict__ Xv, short* __restrict__ Xb) {
  int z = blockIdx.y;
  const float* X = z == 0 ? Xq : (z == 1 ? Xk : Xv);
  short* O = Xb + (size_t)z * M_TOT * D_MODEL;
  size_t i = ((size_t)blockIdx.x * 256 + threadIdx.x) * 8;
  float4 f0 = *(const float4*)(X + i);
  float4 f1 = *(const float4*)(X + i + 4);
  short8 v;
  v[0] = f2bf(f0.x); v[1] = f2bf(f0.y); v[2] = f2bf(f0.z); v[3] = f2bf(f0.w);
  v[4] = f2bf(f1.x); v[5] = f2bf(f1.y); v[6] = f2bf(f1.z); v[7] = f2bf(f1.w);
  *(short8*)(O + i) = v;
}

// ---------------------------------------------------------------------------
// 2) Projections, 128x128 tile, BK=32, DOUBLE-BUFFERED global_load_lds with
//    counted vmcnt (attn-proven pattern): next K-step's loads fly under the
//    current K-step's MFMAs; never drain vmcnt to 0 mid-loop.
// ---------------------------------------------------------------------------
__global__ __launch_bounds__(256) void proj_kernel(
    const short* __restrict__ Xb, const short* __restrict__ WTall,
    short* __restrict__ Qo, short* __restrict__ Ko, short* __restrict__ Vo) {
  int bid = blockIdx.x;
  int wk = (bid & 7) * 72 + (bid >> 3);   // 576 % 8 == 0 -> bijective
  int which = wk / 192;
  int rem = wk % 192;
  int mt = rem / 6, nt = rem % 6;
  int mbase = mt * 128, nbase = nt * 128;
  const short* X = Xb + (size_t)which * M_TOT * D_MODEL;
  const short* WT = WTall + (size_t)which * D_MODEL * D_MODEL;

  __shared__ short As[2][128][32];
  __shared__ short Bs[2][128][32];
  int tid = threadIdx.x;
  int wv = tid >> 6, lane = tid & 63, r = lane & 15, g = lane >> 4;
  int wm = (wv & 1) * 64, wn = (wv >> 1) * 64;
  int srow = (lane >> 2), scol = (lane & 3) * 8;

#define PSTAGE(buf, kk)                                                        \
  {                                                                            \
    _Pragma("unroll") for (int j = 0; j < 2; ++j) {                            \
      int row = wv * 32 + j * 16;                                              \
      gl16(X + (size_t)(mbase + row + srow) * D_MODEL + (kk) + scol,           \
           &As[buf][row][0]);                                                  \
      gl16(WT + (size_t)(nbase + row + srow) * D_MODEL + (kk) + scol,          \
           &Bs[buf][row][0]);                                                  \
    }                                                                          \
  }

  f32x4 acc[4][4] = {};
  PSTAGE(0, 0);
  for (int kt = 0; kt < 24; ++kt) {
    int cur = kt & 1;
    if (kt < 23) {
      PSTAGE(cur ^ 1, (kt + 1) * 32);
      asm volatile("s_waitcnt vmcnt(4)" ::: "memory"); // current tile landed
    } else {
      asm volatile("s_waitcnt vmcnt(0)" ::: "memory");
    }
    __builtin_amdgcn_s_barrier();
    short8 a[4], b[4];
#pragma unroll
    for (int i = 0; i < 4; ++i) {
      a[i] = *(short8*)&As[cur][wm + i * 16 + r][g * 8];
      b[i] = *(short8*)&Bs[cur][wn + i * 16 + r][g * 8];
    }
#pragma unroll
    for (int i = 0; i < 4; ++i)
#pragma unroll
      for (int j = 0; j < 4; ++j)
        acc[i][j] = mfma16(a[i], b[j], acc[i][j]);
    __builtin_amdgcn_s_barrier();
  }
#undef PSTAGE
#pragma unroll
  for (int i = 0; i < 4; ++i)
#pragma unroll
    for (int j = 0; j < 4; ++j)
#pragma unroll
      for (int reg = 0; reg < 4; ++reg) {
        int m = mbase + wm + i * 16 + g * 4 + reg;
        int n = nbase + wn + j * 16 + r;
        int b_ = m >> 11, s = m & 2047, h = n >> 6, d = n & 63;
        if (which == 0) {
          short v = f2bf(acc[i][j][reg] * 0.18033688f); // 1/8 * log2(e)
          Qo[(((size_t)b_ * NH + h) * S_LEN + s) * DK + d] = v;
        } else if (which == 1) {
          short v = f2bf(acc[i][j][reg]);
          Ko[(((size_t)b_ * NH + h) * S_LEN + s) * DK + (d ^ ((s & 7) << 3))] = v;
        } else {
          short v = f2bf(acc[i][j][reg]);
          Vo[(((size_t)b_ * NH + h) * DK + d) * S_LEN + (s ^ ((d & 7) << 3))] = v;
        }
      }
}

// ---------------------------------------------------------------------------
// 3) Flash attention, NO-LDS, hoisted per-lane offsets + K(t+1) register
//    prefetch under the softmax VALU chain. Split-KV=2 + normalized partials.
// ---------------------------------------------------------------------------
__global__ __launch_bounds__(256) void attn_kernel(
    const short* __restrict__ Qg, const short* __restrict__ Kg,
    const short* __restrict__ Vt, short* __restrict__ oP,
    float* __restrict__ mlP) {
  int bh = blockIdx.y;
  int split = blockIdx.z;
  int tid = threadIdx.x;
  int w = tid >> 6, lane = tid & 63;
  int c32 = lane & 31, hi = lane >> 5;
  int qbase = blockIdx.x * 128 + w * 32;
  int kc0 = split * (S_LEN / 2);
  const short* qp = Qg + (size_t)bh * S_LEN * DK;
  const char* kp = (const char*)(Kg + (size_t)bh * S_LEN * DK);
  const char* vp = (const char*)(Vt + (size_t)bh * DK * S_LEN);

  short8 qf[4];
#pragma unroll
  for (int kk = 0; kk < 4; ++kk)
    qf[kk] = *(const short8*)(qp + (size_t)(qbase + c32) * DK + kk * 16 + hi * 8);

  int sw = (c32 & 7) << 4;
  int ko0[4], ko1[4], vo0[4], vo1[4];
#pragma unroll
  for (int i = 0; i < 4; ++i) {
    int cb = i * 32 + hi * 16;
    ko0[i] = c32 * 128 + (cb ^ sw);
    ko1[i] = (32 + c32) * 128 + (cb ^ sw);
    vo0[i] = c32 * 4096 + (cb ^ sw);
    vo1[i] = (32 + c32) * 4096 + (cb ^ sw);
  }

  // K fragments for tile 0
  short8 kr0[4], kr1[4];
  {
    const char* kt0 = kp + (size_t)kc0 * 128;
#pragma unroll
    for (int i = 0; i < 4; ++i) {
      kr0[i] = *(const short8*)(kt0 + ko0[i]);
      kr1[i] = *(const short8*)(kt0 + ko1[i]);
    }
  }

  f32x16 o0 = {}, o1 = {};
  float m_run = -30000.f, l_run = 0.f;
  const int NT = (S_LEN / 2) / 64; // 16

  for (int t = 0; t < NT; ++t) {
    int kc = kc0 + t * 64;
    const char* vt = vp + (size_t)kc * 2;

    // V fragment loads issued first; consumed after softmax (~400cy later)
    short8 vl0[4], vl1[4];
#pragma unroll
    for (int ks = 0; ks < 4; ++ks) {
      vl0[ks] = *(const short8*)(vt + vo0[ks]);
      vl1[ks] = *(const short8*)(vt + vo1[ks]);
    }

    // QK^T from prefetched K registers
    f32x16 st0 = {}, st1 = {};
#pragma unroll
    for (int kk = 0; kk < 4; ++kk) {
      st0 = mfma32(kr0[kk], qf[kk], st0);
      st1 = mfma32(kr1[kk], qf[kk], st1);
    }

    // K(t+1) prefetch: flies under the softmax VALU chain (clamped index;
    // last-tile re-read is cheap and discarded)
    {
      int tn = (t + 1 < NT) ? t + 1 : NT - 1;
      const char* ktn = kp + (size_t)(kc0 + tn * 64) * 128;
#pragma unroll
      for (int i = 0; i < 4; ++i) {
        kr0[i] = *(const short8*)(ktn + ko0[i]);
        kr1[i] = *(const short8*)(ktn + ko1[i]);
      }
    }

    float cm = -30000.f;
#pragma unroll
    for (int i = 0; i < 16; ++i) cm = fmaxf(cm, fmaxf(st0[i], st1[i]));
    cm = fmaxf(cm, __shfl_xor(cm, 32));
    if (!__all(cm <= m_run + 8.0f)) {
      float m_new = fmaxf(m_run, cm);
      float al = __builtin_amdgcn_exp2f(m_run - m_new);
      l_run *= al;
      m_run = m_new;
#pragma unroll
      for (int r = 0; r < 16; ++r) {
        int ql = (r & 3) + 8 * (r >> 2) + 4 * hi;
        float ar = __shfl(al, ql);
        o0[r] *= ar;
        o1[r] *= ar;
      }
    }
    float csum = 0.f;
#pragma unroll
    for (int i = 0; i < 16; ++i) {
      st0[i] = __builtin_amdgcn_exp2f(st0[i] - m_run);
      st1[i] = __builtin_amdgcn_exp2f(st1[i] - m_run);
      csum += st0[i] + st1[i];
    }
    csum += __shfl_xor(csum, 32);
    l_run += csum;

#pragma unroll
    for (int ks = 0; ks < 4; ++ks) {
      f32x16 P = (ks < 2) ? st0 : st1;
      int s8 = (ks & 1) * 8;
      unsigned A = cvtpk(P[s8 + 0], P[s8 + 1]);
      unsigned Bx = cvtpk(P[s8 + 4], P[s8 + 5]);
      unsigned C = cvtpk(P[s8 + 2], P[s8 + 3]);
      unsigned Dx = cvtpk(P[s8 + 6], P[s8 + 7]);
      plswap(A, Bx);
      plswap(C, Dx);
      union { unsigned u[4]; short8 s; } pu;
      pu.u[0] = A; pu.u[1] = C; pu.u[2] = Bx; pu.u[3] = Dx;
      o0 = mfma32(pu.s, vl0[ks], o0);
      o1 = mfma32(pu.s, vl1[ks], o1);
    }
  }

  // epilogue: write NORMALIZED partial + (m,l)
  size_t pbase = ((size_t)split * 24 + bh) * S_LEN;
#pragma unroll
  for (int r = 0; r < 16; ++r) {
    int ql = (r & 3) + 8 * (r >> 2) + 4 * hi;
    float linv = 1.0f / __shfl(l_run, ql);
    short* op = oP + (pbase + qbase + ql) * DK;
    op[c32] = f2bf(o0[r] * linv);
    op[32 + c32] = f2bf(o1[r] * linv);
  }
  if (hi == 0) {
    float* mlp = mlP + (pbase + qbase + c32) * 2;
    mlp[0] = m_run;
    mlp[1] = l_run;
  }
}

// ---------------------------------------------------------------------------
// 3b) Merge split-KV partials -> ctx. Pure interpolation of normalized v_s:
//     a_s = l_s * 2^(m_s - m);  v = (v0*a0 + v1*a1) / (a0 + a1)
// ---------------------------------------------------------------------------
__global__ __launch_bounds__(256) void merge_kernel(
    const short* __restrict__ oP, const float* __restrict__ mlP,
    short* __restrict__ Cx) {
  int t = blockIdx.x * 256 + threadIdx.x;
  int q = t >> 5, dp = (t & 31) * 2;
  const int NQ = 24 * S_LEN;
  float2 ml0 = *(const float2*)(mlP + (size_t)q * 2);
  float2 ml1 = *(const float2*)(mlP + ((size_t)NQ + q) * 2);
  float m = fmaxf(ml0.x, ml1.x);
  float a0 = ml0.y * __builtin_amdgcn_exp2f(ml0.x - m);
  float a1 = ml1.y * __builtin_amdgcn_exp2f(ml1.x - m);
  float inv = 1.0f / (a0 + a1);
  float w0 = a0 * inv, w1 = a1 * inv;
  uint32_t a = *(const uint32_t*)(oP + (size_t)q * DK + dp);
  uint32_t b2 = *(const uint32_t*)(oP + ((size_t)NQ + q) * DK + dp);
  float v0 = lo16(a) * w0 + lo16(b2) * w1;
  float v1 = hi16(a) * w0 + hi16(b2) * w1;
  int bh = q >> 11, sr = q & 2047, b = bh / NH, h = bh % NH;
  uint32_t outw = (uint32_t)(uint16_t)f2bf(v0) | ((uint32_t)(uint16_t)f2bf(v1) << 16);
  *(uint32_t*)(Cx + ((size_t)(b * S_LEN + sr)) * D_MODEL + h * DK + dp) = outw;
}

// ---------------------------------------------------------------------------
// 4a) Y = ctx @ Wo + resid  (f32 out). Double-buffered like proj.
// ---------------------------------------------------------------------------
__global__ __launch_bounds__(256) void gemm_out_kernel(
    const short* __restrict__ ctx, const short* __restrict__ WoT,
    const float* __restrict__ resid, float* __restrict__ Y) {
  int bid = blockIdx.x;
  int wk = (bid & 7) * 24 + (bid >> 3);   // 192 % 8 == 0 -> bijective
  int mt = wk / 6, nt = wk % 6;
  int mbase = mt * 128, nbase = nt * 128;

  __shared__ short As[2][128][32];
  __shared__ short Bs[2][128][32];
  int tid = threadIdx.x;
  int wv = tid >> 6, lane = tid & 63, r = lane & 15, g = lane >> 4;
  int wm = (wv & 1) * 64, wn = (wv >> 1) * 64;
  int srow = (lane >> 2), scol = (lane & 3) * 8;

#define GSTAGE(buf, kk)                                                        \
  {                                                                            \
    _Pragma("unroll") for (int j = 0; j < 2; ++j) {                            \
      int row = wv * 32 + j * 16;                                              \
      gl16(ctx + (size_t)(mbase + row + srow) * D_MODEL + (kk) + scol,         \
           &As[buf][row][0]);                                                  \
      gl16(WoT + (size_t)(nbase + row + srow) * D_MODEL + (kk) + scol,         \
           &Bs[buf][row][0]);                                                  \
    }                                                                          \
  }

  f32x4 acc[4][4] = {};
  GSTAGE(0, 0);
  for (int kt = 0; kt < 24; ++kt) {
    int cur = kt & 1;
    if (kt < 23) {
      GSTAGE(cur ^ 1, (kt + 1) * 32);
      asm volatile("s_waitcnt vmcnt(4)" ::: "memory");
    } else {
      asm volatile("s_waitcnt vmcnt(0)" ::: "memory");
    }
    __builtin_amdgcn_s_barrier();
    short8 a[4], b[4];
#pragma unroll
    for (int i = 0; i < 4; ++i) {
      a[i] = *(short8*)&As[cur][wm + i * 16 + r][g * 8];
      b[i] = *(short8*)&Bs[cur][wn + i * 16 + r][g * 8];
    }
#pragma unroll
    for (int i = 0; i < 4; ++i)
#pragma unroll
      for (int j = 0; j < 4; ++j)
        acc[i][j] = mfma16(a[i], b[j], acc[i][j]);
    __builtin_amdgcn_s_barrier();
  }
#undef GSTAGE
#pragma unroll
  for (int i = 0; i < 4; ++i)
#pragma unroll
    for (int j = 0; j < 4; ++j)
#pragma unroll
      for (int reg = 0; reg < 4; ++reg) {
        int m = mbase + wm + i * 16 + g * 4 + reg;
        int n = nbase + wn + j * 16 + r;
        Y[(size_t)m * D_MODEL + n] = acc[i][j][reg] + resid[(size_t)m * D_MODEL + n];
      }
}

// ---------------------------------------------------------------------------
// 4b) LayerNorm over Y rows (wave per row). Y already includes residual.
// ---------------------------------------------------------------------------
__global__ __launch_bounds__(256) void ln_kernel(const float* __restrict__ Y,
                                                 float* __restrict__ out) {
  int row = blockIdx.x * 4 + (threadIdx.x >> 6);
  int l = threadIdx.x & 63;
  const float* yp = Y + (size_t)row * D_MODEL;
  float v[12];
  float s = 0.f, q = 0.f;
#pragma unroll
  for (int c = 0; c < 12; ++c) {
    v[c] = yp[c * 64 + l];
    s += v[c];
    q += v[c] * v[c];
  }
#pragma unroll
  for (int d = 1; d < 64; d <<= 1) {
    s += __shfl_xor(s, d);
    q += __shfl_xor(q, d);
  }
  float mu = s * (1.0f / 768.0f);
  float var = q * (1.0f / 768.0f) - mu * mu;
  float rstd = rsqrtf(var + 1e-5f);
  float* op = out + (size_t)row * D_MODEL;
#pragma unroll
  for (int c = 0; c < 12; ++c)
    op[c * 64 + l] = (v[c] - mu) * rstd;
}

// ---------------------------------------------------------------------------
extern "C" void kernel_launch(void* const* d_in, const int* in_sizes, int n_in,
                              void* d_out, int out_size, void* d_ws, size_t ws_size,
                              hipStream_t stream) {
  const float* xq = (const float*)d_in[0];
  const float* xk = (const float*)d_in[1];
  const float* xv = (const float*)d_in[2];
  const float* Wq = (const float*)d_in[3];
  const float* Wk = (const float*)d_in[4];
  const float* Wv = (const float*)d_in[5];
  const float* Wo = (const float*)d_in[6];
  float* out = (float*)d_out;

  char* ws = (char*)d_ws;
  const size_t WSZ = (size_t)D_MODEL * D_MODEL;   // 589824
  const size_t QSZ = (size_t)M_TOT * D_MODEL;     // 3145728
  short* WT = (short*)ws;                         // 4 * WSZ
  short* Xb = WT + 4 * WSZ;                       // 3 * QSZ (bf16 activations)
  short* Qb = Xb + 3 * QSZ;
  short* Kb = Qb + QSZ;
  short* Vb = Kb + QSZ;
  short* Cx = Vb + QSZ;
  // aliases into dead Xb region (Xb consumed by proj before attn writes):
  short* oP = Xb;                                          // 12.6 MB
  float* mlP = (float*)(Xb + (size_t)2 * 24 * S_LEN * DK); // 786 KB
  float* Yf = (float*)Xb;  // used after merge consumed partials

  transpose_w_kernel<<<dim3(24, 24, 4), dim3(32, 8), 0, stream>>>(Wq, Wk, Wv, Wo, WT);
  cast_x_kernel<<<dim3(1536, 3), 256, 0, stream>>>(xq, xk, xv, Xb);
  proj_kernel<<<576, 256, 0, stream>>>(Xb, WT, Qb, Kb, Vb);
  attn_kernel<<<dim3(16, 24, 2), 256, 0, stream>>>(Qb, Kb, Vb, oP, mlP);
  merge_kernel<<<6144, 256, 0, stream>>>(oP, mlP, Cx);
  gemm_out_kernel<<<192, 256, 0, stream>>>(Cx, WT + 3 * WSZ, xq, Yf);
  ln_kernel<<<1024, 256, 0, stream>>>(Yf, out);
}